// Round 1
// baseline (1663.425 us; speedup 1.0000x reference)
//
#include <hip/hip_runtime.h>
#include <hip/hip_bf16.h>

#define B_    2
#define S_    2048
#define D_    1024
#define H_    16
#define KV_   4
#define QKB_  16
#define VB_   32
#define NTOK  (B_ * S_)   // 4096

__device__ __forceinline__ float sigmoidf_(float x) {
    return 1.0f / (1.0f + __expf(-x));
}

// ---------------- Kernel 1: QKV projection + sigmoid + head-major scatter ----------------
// hs[4096,1024] @ [Wq|Wk|Wv] (448 cols) ; tile 64x64, BK=16, 256 thr, 4x4 microtile.
__global__ __launch_bounds__(256) void proj_kernel(
    const float* __restrict__ hs, const float* __restrict__ Wq,
    const float* __restrict__ Wk, const float* __restrict__ Wv,
    float* __restrict__ pq, float* __restrict__ pk, float* __restrict__ pv)
{
    __shared__ float As[16][68];
    __shared__ float Bs[16][68];
    const int tid = threadIdx.x;
    const int m0  = blockIdx.x * 64;
    const int by  = blockIdx.y;

    const float* Wsel; int ldw, nbase;
    if (by < 4)       { Wsel = Wq; ldw = 256; nbase = by * 64; }
    else if (by == 4) { Wsel = Wk; ldw = 64;  nbase = 0; }
    else              { Wsel = Wv; ldw = 128; nbase = (by - 5) * 64; }

    const int row4 = (tid >> 4) << 2;
    const int col4 = (tid & 15) << 2;
    const int am = tid >> 2, ak = (tid & 3) << 2;
    const int bk = tid >> 4, bn = (tid & 15) << 2;

    float c[4][4] = {};

    for (int k0 = 0; k0 < D_; k0 += 16) {
        float4 av = *(const float4*)(hs + (m0 + am) * D_ + k0 + ak);
        As[ak + 0][am] = av.x; As[ak + 1][am] = av.y;
        As[ak + 2][am] = av.z; As[ak + 3][am] = av.w;
        *(float4*)&Bs[bk][bn] = *(const float4*)(Wsel + (k0 + bk) * ldw + nbase + bn);
        __syncthreads();
        #pragma unroll
        for (int k = 0; k < 16; ++k) {
            float4 a = *(const float4*)&As[k][row4];
            float4 b = *(const float4*)&Bs[k][col4];
            float aa[4] = {a.x, a.y, a.z, a.w};
            float bb[4] = {b.x, b.y, b.z, b.w};
            #pragma unroll
            for (int i = 0; i < 4; ++i)
                #pragma unroll
                for (int j = 0; j < 4; ++j)
                    c[i][j] = fmaf(aa[i], bb[j], c[i][j]);
        }
        __syncthreads();
    }

    #pragma unroll
    for (int i = 0; i < 4; ++i) {
        const int tok = m0 + row4 + i;
        const int b = tok >> 11, s = tok & (S_ - 1);
        #pragma unroll
        for (int j = 0; j < 4; ++j) {
            const int n = by * 64 + col4 + j;
            const float val = sigmoidf_(c[i][j]);
            if (n < 256) {
                const int h = n >> 4, d = n & 15;
                pq[(((b * H_ + h) * S_) + s) * QKB_ + d] = val;
            } else if (n < 320) {
                const int jj = n - 256, kv = jj >> 4, d = jj & 15;
                pk[(((b * KV_ + kv) * S_) + s) * QKB_ + d] = val;
            } else {
                const int jj = n - 320, kv = jj >> 5, d = jj & 31;
                pv[(((b * KV_ + kv) * S_) + s) * VB_ + d] = val;
            }
        }
    }
}

// ---------------- Kernel 2: causal soft-binary attention (flash-style) ----------------
// Block: 64 queries (lane = query), 4 waves each take a 32-key stripe of every
// 128-key LDS tile; online softmax; stripe-merge via LDS; writes xo = e0+(e1-e0)*vh.
#define LOG2E_ 1.44269504088896340736f

struct TileBuf {
    float pk[128][QKB_];
    float pv[128][VB_];
    float sumk[128];
};
struct MergeBuf {
    float m[3][64];
    float l[3][64];
    float acc[3][64][VB_];
};

__global__ __launch_bounds__(256) void attn_kernel(
    const float* __restrict__ pqg, const float* __restrict__ pkg,
    const float* __restrict__ pvg, const float* __restrict__ e0,
    const float* __restrict__ e1, float* __restrict__ xo)
{
    __shared__ __align__(16) char smem[sizeof(MergeBuf) > sizeof(TileBuf) ? sizeof(MergeBuf) : sizeof(TileBuf)];
    TileBuf*  tb = (TileBuf*)smem;
    MergeBuf* mb = (MergeBuf*)smem;

    const int tid  = threadIdx.x;
    const int lane = tid & 63;
    const int wave = tid >> 6;
    const int qt = blockIdx.x & 31;        // S/64 = 32 query tiles
    const int bh = blockIdx.x >> 5;        // 0..31
    const int b = bh >> 4, h = bh & 15;
    const int kv = h >> 2;                 // N_REP = 4
    const int q = qt * 64 + lane;

    float qf[16];
    {
        const float4* src = (const float4*)(pqg + (((b * H_ + h) * S_) + q) * QKB_);
        #pragma unroll
        for (int i = 0; i < 4; ++i) {
            float4 v = src[i];
            qf[4*i+0] = v.x; qf[4*i+1] = v.y; qf[4*i+2] = v.z; qf[4*i+3] = v.w;
        }
    }

    float m = -1e30f, l = 0.f;
    float acc[VB_];
    #pragma unroll
    for (int d = 0; d < VB_; ++d) acc[d] = 0.f;

    const int ntiles = (qt >> 1) + 1;
    const float* pkbase = pkg + ((b * KV_ + kv) * S_) * QKB_;
    const float* pvbase = pvg + ((b * KV_ + kv) * S_) * VB_;

    for (int tile = 0; tile < ntiles; ++tile) {
        const int t0 = tile * 128;
        {   // stage pk (2048 floats) + pv (4096 floats) cooperatively
            const float4* src = (const float4*)(pkbase + t0 * QKB_);
            float4* dst = (float4*)tb->pk;
            dst[tid]       = src[tid];
            dst[tid + 256] = src[tid + 256];
            const float4* vsrc = (const float4*)(pvbase + t0 * VB_);
            float4* vdst = (float4*)tb->pv;
            #pragma unroll
            for (int i = 0; i < 4; ++i) vdst[tid + i * 256] = vsrc[tid + i * 256];
        }
        __syncthreads();
        if (tid < 128) {
            float ssum = 0.f;
            #pragma unroll
            for (int d = 0; d < QKB_; ++d) ssum += tb->pk[tid][d];
            tb->sumk[tid] = ssum;
        }
        __syncthreads();

        #pragma unroll
        for (int c0 = 0; c0 < 32; c0 += 16) {
            float sc[16];
            #pragma unroll
            for (int kk = 0; kk < 16; ++kk) {
                const int tk = wave * 32 + c0 + kk;
                const int t  = t0 + tk;
                const float4* kr = (const float4*)tb->pk[tk];
                float dot = 0.f;
                #pragma unroll
                for (int i2 = 0; i2 < 4; ++i2) {
                    float4 kvv = kr[i2];
                    dot = fmaf(qf[4*i2+0], kvv.x, dot);
                    dot = fmaf(qf[4*i2+1], kvv.y, dot);
                    dot = fmaf(qf[4*i2+2], kvv.z, dot);
                    dot = fmaf(qf[4*i2+3], kvv.w, dot);
                }
                sc[kk] = (t <= q) ? (2.f * dot - tb->sumk[tk]) : -1e30f;
            }
            float cmax = sc[0];
            #pragma unroll
            for (int kk = 1; kk < 16; ++kk) cmax = fmaxf(cmax, sc[kk]);
            const float m_new = fmaxf(m, cmax);
            const float alpha = __expf(m - m_new);
            l *= alpha;
            #pragma unroll
            for (int d = 0; d < VB_; ++d) acc[d] *= alpha;
            m = m_new;
            #pragma unroll
            for (int kk = 0; kk < 16; ++kk) {
                const int tk = wave * 32 + c0 + kk;
                const float p = (sc[kk] < -1e29f) ? 0.f : __expf(sc[kk] - m);
                l += p;
                const float4* vr = (const float4*)tb->pv[tk];
                #pragma unroll
                for (int i2 = 0; i2 < 8; ++i2) {
                    float4 vv = vr[i2];
                    acc[4*i2+0] = fmaf(p, vv.x, acc[4*i2+0]);
                    acc[4*i2+1] = fmaf(p, vv.y, acc[4*i2+1]);
                    acc[4*i2+2] = fmaf(p, vv.z, acc[4*i2+2]);
                    acc[4*i2+3] = fmaf(p, vv.w, acc[4*i2+3]);
                }
            }
        }
        __syncthreads();   // protect LDS before next tile's staging
    }

    // merge the 4 stripes (wave 0 gathers)
    if (wave > 0) {
        mb->m[wave-1][lane] = m;
        mb->l[wave-1][lane] = l;
        #pragma unroll
        for (int d = 0; d < VB_; ++d) mb->acc[wave-1][lane][d] = acc[d];
    }
    __syncthreads();
    if (wave == 0) {
        #pragma unroll
        for (int sidx = 0; sidx < 3; ++sidx) {
            const float ms = mb->m[sidx][lane];
            const float ls = mb->l[sidx][lane];
            const float mn = fmaxf(m, ms);
            const float a0 = __expf(m - mn);
            const float a1 = (ms < -1e29f) ? 0.f : __expf(ms - mn);
            l = l * a0 + ls * a1;
            #pragma unroll
            for (int d = 0; d < VB_; ++d)
                acc[d] = acc[d] * a0 + mb->acc[sidx][lane][d] * a1;
            m = mn;
        }
        const float inv_l = 1.f / l;
        const int tok = b * S_ + q;
        float* dst = xo + tok * (H_ * VB_) + h * VB_;
        #pragma unroll
        for (int i2 = 0; i2 < 8; ++i2) {
            const int idx = h * VB_ + 4 * i2;
            float4 o;
            o.x = e0[idx+0] + (e1[idx+0] - e0[idx+0]) * (acc[4*i2+0] * inv_l);
            o.y = e0[idx+1] + (e1[idx+1] - e0[idx+1]) * (acc[4*i2+1] * inv_l);
            o.z = e0[idx+2] + (e1[idx+2] - e0[idx+2]) * (acc[4*i2+2] * inv_l);
            o.w = e0[idx+3] + (e1[idx+3] - e0[idx+3]) * (acc[4*i2+3] * inv_l);
            *(float4*)(dst + 4 * i2) = o;
        }
    }
}

// ---------------- Kernel 3: output projection xo[4096,512] @ Wo[512,1024] ----------------
__global__ __launch_bounds__(256) void outproj_kernel(
    const float* __restrict__ xo, const float* __restrict__ Wo,
    float* __restrict__ out)
{
    __shared__ float As[16][68];
    __shared__ float Bs[16][68];
    const int tid = threadIdx.x;
    const int m0 = blockIdx.x * 64;
    const int n0 = blockIdx.y * 64;
    const int row4 = (tid >> 4) << 2;
    const int col4 = (tid & 15) << 2;
    const int am = tid >> 2, ak = (tid & 3) << 2;
    const int bk = tid >> 4, bn = (tid & 15) << 2;
    float c[4][4] = {};

    for (int k0 = 0; k0 < 512; k0 += 16) {
        float4 av = *(const float4*)(xo + (m0 + am) * 512 + k0 + ak);
        As[ak + 0][am] = av.x; As[ak + 1][am] = av.y;
        As[ak + 2][am] = av.z; As[ak + 3][am] = av.w;
        *(float4*)&Bs[bk][bn] = *(const float4*)(Wo + (k0 + bk) * D_ + n0 + bn);
        __syncthreads();
        #pragma unroll
        for (int k = 0; k < 16; ++k) {
            float4 a = *(const float4*)&As[k][row4];
            float4 b = *(const float4*)&Bs[k][col4];
            float aa[4] = {a.x, a.y, a.z, a.w};
            float bb[4] = {b.x, b.y, b.z, b.w};
            #pragma unroll
            for (int i = 0; i < 4; ++i)
                #pragma unroll
                for (int j = 0; j < 4; ++j)
                    c[i][j] = fmaf(aa[i], bb[j], c[i][j]);
        }
        __syncthreads();
    }

    #pragma unroll
    for (int i = 0; i < 4; ++i) {
        float4 o = {c[i][0], c[i][1], c[i][2], c[i][3]};
        *(float4*)(out + (m0 + row4 + i) * D_ + n0 + col4) = o;
    }
}

extern "C" void kernel_launch(void* const* d_in, const int* in_sizes, int n_in,
                              void* d_out, int out_size, void* d_ws, size_t ws_size,
                              hipStream_t stream)
{
    const float* hs = (const float*)d_in[0];
    const float* Wq = (const float*)d_in[1];
    const float* Wk = (const float*)d_in[2];
    const float* Wv = (const float*)d_in[3];
    const float* Wo = (const float*)d_in[4];
    const float* e0 = (const float*)d_in[5];
    const float* e1 = (const float*)d_in[6];
    float* out = (float*)d_out;

    float* ws = (float*)d_ws;
    float* pq = ws;                               // [B,H,S,16]  1,048,576 f
    float* pk = pq + B_ * H_ * S_ * QKB_;         // [B,KV,S,16]   262,144 f
    float* pv = pk + B_ * KV_ * S_ * QKB_;        // [B,KV,S,32]   524,288 f
    float* xo = pv + B_ * KV_ * S_ * VB_;         // [B,S,512]   2,097,152 f

    proj_kernel<<<dim3(NTOK / 64, 7), 256, 0, stream>>>(hs, Wq, Wk, Wv, pq, pk, pv);
    attn_kernel<<<dim3(B_ * H_ * (S_ / 64)), 256, 0, stream>>>(pq, pk, pv, e0, e1, xo);
    outproj_kernel<<<dim3(NTOK / 64, D_ / 64), 256, 0, stream>>>(xo, Wo, out);
}

// Round 2
// 404.637 us; speedup vs baseline: 4.1109x; 4.1109x over previous
//
#include <hip/hip_runtime.h>
#include <hip/hip_bf16.h>

#define B_    2
#define S_    2048
#define D_    1024
#define H_    16
#define KV_   4
#define QKB_  16
#define VB_   32
#define NTOK  (B_ * S_)   // 4096

__device__ __forceinline__ float sigmoidf_(float x) {
    return 1.0f / (1.0f + __expf(-x));
}

// ---------------- Kernel 1: QKV projection + sigmoid + head-major scatter ----------------
__global__ __launch_bounds__(256) void proj_kernel(
    const float* __restrict__ hs, const float* __restrict__ Wq,
    const float* __restrict__ Wk, const float* __restrict__ Wv,
    float* __restrict__ pq, float* __restrict__ pk, float* __restrict__ pv)
{
    __shared__ float As[16][68];
    __shared__ float Bs[16][68];
    const int tid = threadIdx.x;
    const int m0  = blockIdx.x * 64;
    const int by  = blockIdx.y;

    const float* Wsel; int ldw, nbase;
    if (by < 4)       { Wsel = Wq; ldw = 256; nbase = by * 64; }
    else if (by == 4) { Wsel = Wk; ldw = 64;  nbase = 0; }
    else              { Wsel = Wv; ldw = 128; nbase = (by - 5) * 64; }

    const int row4 = (tid >> 4) << 2;
    const int col4 = (tid & 15) << 2;
    const int am = tid >> 2, ak = (tid & 3) << 2;
    const int bk = tid >> 4, bn = (tid & 15) << 2;

    float c[4][4] = {};

    for (int k0 = 0; k0 < D_; k0 += 16) {
        float4 av = *(const float4*)(hs + (m0 + am) * D_ + k0 + ak);
        As[ak + 0][am] = av.x; As[ak + 1][am] = av.y;
        As[ak + 2][am] = av.z; As[ak + 3][am] = av.w;
        *(float4*)&Bs[bk][bn] = *(const float4*)(Wsel + (k0 + bk) * ldw + nbase + bn);
        __syncthreads();
        #pragma unroll
        for (int k = 0; k < 16; ++k) {
            float4 a = *(const float4*)&As[k][row4];
            float4 b = *(const float4*)&Bs[k][col4];
            float aa[4] = {a.x, a.y, a.z, a.w};
            float bb[4] = {b.x, b.y, b.z, b.w};
            #pragma unroll
            for (int i = 0; i < 4; ++i)
                #pragma unroll
                for (int j = 0; j < 4; ++j)
                    c[i][j] = fmaf(aa[i], bb[j], c[i][j]);
        }
        __syncthreads();
    }

    #pragma unroll
    for (int i = 0; i < 4; ++i) {
        const int tok = m0 + row4 + i;
        const int b = tok >> 11, s = tok & (S_ - 1);
        #pragma unroll
        for (int j = 0; j < 4; ++j) {
            const int n = by * 64 + col4 + j;
            const float val = sigmoidf_(c[i][j]);
            if (n < 256) {
                const int h = n >> 4, d = n & 15;
                pq[(((b * H_ + h) * S_) + s) * QKB_ + d] = val;
            } else if (n < 320) {
                const int jj = n - 256, kv = jj >> 4, d = jj & 15;
                pk[(((b * KV_ + kv) * S_) + s) * QKB_ + d] = val;
            } else {
                const int jj = n - 320, kv = jj >> 5, d = jj & 31;
                pv[(((b * KV_ + kv) * S_) + s) * VB_ + d] = val;
            }
        }
    }
}

// ---------------- Kernel 2: causal soft-binary attention ----------------
// Math: score/tau = QKB - sum(pq) - sum(pk) + 2*pq.pk.  Softmax is invariant to
// the per-row constant (QKB - sum(pq)); shifting by sum(pq) gives exponent
//   e = dot(2*pq-1, pk) - sum(pq)  in [-QKB, 0]  -> exp never overflows, so
// NO online max / rescale is needed.  p = exp(e); l = sum p; out = (p.V)/l.
//
// Block: 64 queries (lane = query), 4 waves each take a 32-key stripe of every
// 128-key LDS tile; stripes merged through LDS at the end.

struct TileBuf {
    float pk[128][QKB_];   //  8 KB
    float pv[128][VB_];    // 16 KB
};
struct MergeBuf {
    float l[3][64];        // 768 B
    float acc[3][64][33];  // 25.3 KB (stride 33: bank = lane+d mod 32, conflict-free)
};

__global__ __launch_bounds__(256, 4) void attn_kernel(
    const float* __restrict__ pqg, const float* __restrict__ pkg,
    const float* __restrict__ pvg, const float* __restrict__ e0,
    const float* __restrict__ e1, float* __restrict__ xo)
{
    __shared__ __align__(16) char smem[sizeof(MergeBuf) > sizeof(TileBuf) ? sizeof(MergeBuf) : sizeof(TileBuf)];
    TileBuf*  tb = (TileBuf*)smem;
    MergeBuf* mb = (MergeBuf*)smem;

    const int tid  = threadIdx.x;
    const int lane = tid & 63;
    const int wave = tid >> 6;
    const int qt = blockIdx.x & 31;        // S/64 = 32 query tiles
    const int bh = blockIdx.x >> 5;        // 0..31
    const int b = bh >> 4, h = bh & 15;
    const int kv = h >> 2;                 // N_REP = 4
    const int q = qt * 64 + lane;
    const int qmax_blk = qt * 64 + 63;

    // Load q row; build qg = 2*pq-1 and qsum = sum(pq).
    float qg[QKB_];
    float qsum = 0.f;
    {
        const float4* src = (const float4*)(pqg + (((b * H_ + h) * S_) + q) * QKB_);
        #pragma unroll
        for (int i = 0; i < 4; ++i) {
            float4 v = src[i];
            qsum += v.x + v.y + v.z + v.w;
            qg[4*i+0] = 2.f * v.x - 1.f;
            qg[4*i+1] = 2.f * v.y - 1.f;
            qg[4*i+2] = 2.f * v.z - 1.f;
            qg[4*i+3] = 2.f * v.w - 1.f;
        }
    }

    float l = 0.f;
    float acc[VB_];
    #pragma unroll
    for (int d = 0; d < VB_; ++d) acc[d] = 0.f;

    const int ntiles = (qt >> 1) + 1;
    const float* pkbase = pkg + ((b * KV_ + kv) * S_) * QKB_;
    const float* pvbase = pvg + ((b * KV_ + kv) * S_) * VB_;

    for (int tile = 0; tile < ntiles; ++tile) {
        const int t0 = tile * 128;
        {   // stage pk (2048 floats) + pv (4096 floats) cooperatively
            const float4* src = (const float4*)(pkbase + t0 * QKB_);
            float4* dst = (float4*)tb->pk;
            dst[tid]       = src[tid];
            dst[tid + 256] = src[tid + 256];
            const float4* vsrc = (const float4*)(pvbase + t0 * VB_);
            float4* vdst = (float4*)tb->pv;
            #pragma unroll
            for (int i = 0; i < 4; ++i) vdst[tid + i * 256] = vsrc[tid + i * 256];
        }
        __syncthreads();

        if (t0 + wave * 32 <= qmax_blk) {   // skip fully-masked stripes
            #pragma unroll 2
            for (int kk = 0; kk < 32; ++kk) {
                const int tk = wave * 32 + kk;
                const int t  = t0 + tk;
                const float4* kr = (const float4*)tb->pk[tk];
                float dot = -qsum;
                #pragma unroll
                for (int i2 = 0; i2 < 4; ++i2) {
                    float4 kvv = kr[i2];
                    dot = fmaf(qg[4*i2+0], kvv.x, dot);
                    dot = fmaf(qg[4*i2+1], kvv.y, dot);
                    dot = fmaf(qg[4*i2+2], kvv.z, dot);
                    dot = fmaf(qg[4*i2+3], kvv.w, dot);
                }
                const float p = (t <= q) ? __expf(dot) : 0.f;
                l += p;
                const float4* vr = (const float4*)tb->pv[tk];
                #pragma unroll
                for (int i2 = 0; i2 < 8; ++i2) {
                    float4 vv = vr[i2];
                    acc[4*i2+0] = fmaf(p, vv.x, acc[4*i2+0]);
                    acc[4*i2+1] = fmaf(p, vv.y, acc[4*i2+1]);
                    acc[4*i2+2] = fmaf(p, vv.z, acc[4*i2+2]);
                    acc[4*i2+3] = fmaf(p, vv.w, acc[4*i2+3]);
                }
            }
        }
        __syncthreads();   // protect LDS before next tile's staging
    }

    // merge the 4 stripes (wave 0 gathers); stride-33 rows are conflict-free
    if (wave > 0) {
        mb->l[wave-1][lane] = l;
        #pragma unroll
        for (int d = 0; d < VB_; ++d) mb->acc[wave-1][lane][d] = acc[d];
    }
    __syncthreads();
    if (wave == 0) {
        #pragma unroll
        for (int sidx = 0; sidx < 3; ++sidx) {
            l += mb->l[sidx][lane];
            #pragma unroll
            for (int d = 0; d < VB_; ++d)
                acc[d] += mb->acc[sidx][lane][d];
        }
        const float inv_l = 1.f / l;
        const int tok = b * S_ + q;
        float* dst = xo + tok * (H_ * VB_) + h * VB_;
        #pragma unroll
        for (int i2 = 0; i2 < 8; ++i2) {
            const int idx = h * VB_ + 4 * i2;
            float4 o;
            o.x = e0[idx+0] + (e1[idx+0] - e0[idx+0]) * (acc[4*i2+0] * inv_l);
            o.y = e0[idx+1] + (e1[idx+1] - e0[idx+1]) * (acc[4*i2+1] * inv_l);
            o.z = e0[idx+2] + (e1[idx+2] - e0[idx+2]) * (acc[4*i2+2] * inv_l);
            o.w = e0[idx+3] + (e1[idx+3] - e0[idx+3]) * (acc[4*i2+3] * inv_l);
            *(float4*)(dst + 4 * i2) = o;
        }
    }
}

// ---------------- Kernel 3: output projection xo[4096,512] @ Wo[512,1024] ----------------
__global__ __launch_bounds__(256) void outproj_kernel(
    const float* __restrict__ xo, const float* __restrict__ Wo,
    float* __restrict__ out)
{
    __shared__ float As[16][68];
    __shared__ float Bs[16][68];
    const int tid = threadIdx.x;
    const int m0 = blockIdx.x * 64;
    const int n0 = blockIdx.y * 64;
    const int row4 = (tid >> 4) << 2;
    const int col4 = (tid & 15) << 2;
    const int am = tid >> 2, ak = (tid & 3) << 2;
    const int bk = tid >> 4, bn = (tid & 15) << 2;
    float c[4][4] = {};

    for (int k0 = 0; k0 < 512; k0 += 16) {
        float4 av = *(const float4*)(xo + (m0 + am) * 512 + k0 + ak);
        As[ak + 0][am] = av.x; As[ak + 1][am] = av.y;
        As[ak + 2][am] = av.z; As[ak + 3][am] = av.w;
        *(float4*)&Bs[bk][bn] = *(const float4*)(Wo + (k0 + bk) * D_ + n0 + bn);
        __syncthreads();
        #pragma unroll
        for (int k = 0; k < 16; ++k) {
            float4 a = *(const float4*)&As[k][row4];
            float4 b = *(const float4*)&Bs[k][col4];
            float aa[4] = {a.x, a.y, a.z, a.w};
            float bb[4] = {b.x, b.y, b.z, b.w};
            #pragma unroll
            for (int i = 0; i < 4; ++i)
                #pragma unroll
                for (int j = 0; j < 4; ++j)
                    c[i][j] = fmaf(aa[i], bb[j], c[i][j]);
        }
        __syncthreads();
    }

    #pragma unroll
    for (int i = 0; i < 4; ++i) {
        float4 o = {c[i][0], c[i][1], c[i][2], c[i][3]};
        *(float4*)(out + (m0 + row4 + i) * D_ + n0 + col4) = o;
    }
}

extern "C" void kernel_launch(void* const* d_in, const int* in_sizes, int n_in,
                              void* d_out, int out_size, void* d_ws, size_t ws_size,
                              hipStream_t stream)
{
    const float* hs = (const float*)d_in[0];
    const float* Wq = (const float*)d_in[1];
    const float* Wk = (const float*)d_in[2];
    const float* Wv = (const float*)d_in[3];
    const float* Wo = (const float*)d_in[4];
    const float* e0 = (const float*)d_in[5];
    const float* e1 = (const float*)d_in[6];
    float* out = (float*)d_out;

    float* ws = (float*)d_ws;
    float* pq = ws;                               // [B,H,S,16]  1,048,576 f
    float* pk = pq + B_ * H_ * S_ * QKB_;         // [B,KV,S,16]   262,144 f
    float* pv = pk + B_ * KV_ * S_ * QKB_;        // [B,KV,S,32]   524,288 f
    float* xo = pv + B_ * KV_ * S_ * VB_;         // [B,S,512]   2,097,152 f

    proj_kernel<<<dim3(NTOK / 64, 7), 256, 0, stream>>>(hs, Wq, Wk, Wv, pq, pk, pv);
    attn_kernel<<<dim3(B_ * H_ * (S_ / 64)), 256, 0, stream>>>(pq, pk, pv, e0, e1, xo);
    outproj_kernel<<<dim3(NTOK / 64, D_ / 64), 256, 0, stream>>>(xo, Wo, out);
}

// Round 4
// 181.882 us; speedup vs baseline: 9.1457x; 2.2247x over previous
//
#include <hip/hip_runtime.h>
#include <hip/hip_bf16.h>

#define B_    2
#define S_    2048
#define D_    1024
#define H_    16
#define KV_   4
#define QKB_  16
#define VB_   32
#define NTOK  (B_ * S_)   // 4096
#define L2E_  1.44269504088896f

typedef __attribute__((ext_vector_type(8))) short bshort8;
typedef __attribute__((ext_vector_type(4))) float f32x4;

__device__ __forceinline__ unsigned short bf16_rne(float x) {
    unsigned u = __float_as_uint(x);
    return (unsigned short)((u + 0x7FFFu + ((u >> 16) & 1u)) >> 16);
}
__device__ __forceinline__ unsigned bf16x2_rne(float lo, float hi) {
    return (unsigned)bf16_rne(lo) | ((unsigned)bf16_rne(hi) << 16);
}
__device__ __forceinline__ float bf16_to_f(unsigned short u) {
    return __uint_as_float(((unsigned)u) << 16);
}

// ---------------- Prep 1: hs fp32 -> bf16 ----------------
__global__ __launch_bounds__(256) void cvt_hs_kernel(
    const float* __restrict__ src, unsigned short* __restrict__ dst)
{
    int i = blockIdx.x * 256 + threadIdx.x;      // 8 elems per thread
    const float4* s = (const float4*)src;
    float4 a = s[2 * i], b = s[2 * i + 1];
    uint4 o;
    o.x = bf16x2_rne(a.x, a.y); o.y = bf16x2_rne(a.z, a.w);
    o.z = bf16x2_rne(b.x, b.y); o.w = bf16x2_rne(b.z, b.w);
    ((uint4*)dst)[i] = o;
}

// ---------------- Prep 2: transpose weights to [n][k] bf16 ----------------
// Wcat_t[448][1024]: rows 0-255 Wq cols, 256-319 Wk, 320-447 Wv. Wot[1024][512].
__global__ __launch_bounds__(256) void trans_w_kernel(
    const float* __restrict__ Wq, const float* __restrict__ Wk,
    const float* __restrict__ Wv, const float* __restrict__ Wo,
    unsigned short* __restrict__ Wcat_t, unsigned short* __restrict__ Wot)
{
    __shared__ float T[64][65];
    const int bid = blockIdx.x, t = threadIdx.x;
    const float* src; unsigned short* dst; int K, N, tk, tn, drow0;
    if (bid < 64)       { src = Wq; dst = Wcat_t; K = 1024; N = 256;  int r = bid;       tk = r & 15; tn = r >> 4; drow0 = 0; }
    else if (bid < 80)  { src = Wk; dst = Wcat_t; K = 1024; N = 64;   int r = bid - 64;  tk = r;      tn = 0;      drow0 = 256; }
    else if (bid < 112) { src = Wv; dst = Wcat_t; K = 1024; N = 128;  int r = bid - 80;  tk = r & 15; tn = r >> 4; drow0 = 320; }
    else                { src = Wo; dst = Wot;    K = 512;  N = 1024; int r = bid - 112; tk = r & 7;  tn = r >> 3; drow0 = 0; }
    const int k0 = tk * 64, n0 = tn * 64;
    const int rr = t >> 4, cc = (t & 15) * 4;
    #pragma unroll
    for (int i = 0; i < 4; ++i) {
        float4 v = *(const float4*)(src + (k0 + rr + i * 16) * N + n0 + cc);
        T[rr + i * 16][cc + 0] = v.x; T[rr + i * 16][cc + 1] = v.y;
        T[rr + i * 16][cc + 2] = v.z; T[rr + i * 16][cc + 3] = v.w;
    }
    __syncthreads();
    const int nloc = t >> 2, kc = (t & 3) * 16;
    unsigned o[8];
    #pragma unroll
    for (int j = 0; j < 8; ++j)
        o[j] = bf16x2_rne(T[kc + 2 * j][nloc], T[kc + 2 * j + 1][nloc]);
    unsigned short* dp = dst + (drow0 + n0 + nloc) * K + k0 + kc;
    uint4 w0; w0.x = o[0]; w0.y = o[1]; w0.z = o[2]; w0.w = o[3];
    uint4 w1; w1.x = o[4]; w1.y = o[5]; w1.z = o[6]; w1.w = o[7];
    *(uint4*)(dp) = w0;
    *(uint4*)(dp + 8) = w1;
}

// ---------------- bf16 MFMA GEMM: C[128 x BN] tiles, BK=32 ----------------
// A[M][K] bf16 row-major; Bt[N][K] bf16 (pre-transposed). 4 waves, wave does
// 32 rows x BN cols. EPI=1: proj epilogue (sigmoid + scatter). EPI=0: f32 out.
template<int BN, int EPI>
__global__ __launch_bounds__(256) void gemm_kernel(
    const unsigned short* __restrict__ Ab, const unsigned short* __restrict__ Btb,
    const int K, float* __restrict__ out,
    unsigned short* __restrict__ qg, unsigned short* __restrict__ pko,
    unsigned short* __restrict__ pvT)
{
    __shared__ unsigned short As[128][40];   // stride 40 bf16: frag reads at bank floor
    __shared__ unsigned short Bs[BN][40];
    const int tid = threadIdx.x, l = tid & 63, wq = tid >> 6;
    const int l15 = l & 15, quad = l >> 4;
    const int m0 = blockIdx.x * 128, n0 = blockIdx.y * BN;
    f32x4 c[2][BN / 16];
    #pragma unroll
    for (int i = 0; i < 2; ++i)
        #pragma unroll
        for (int j = 0; j < BN / 16; ++j) c[i][j] = (f32x4){0.f, 0.f, 0.f, 0.f};

    for (int k0 = 0; k0 < K; k0 += 32) {
        #pragma unroll
        for (int it = 0; it < 2; ++it) {
            int ch = tid + it * 256;
            int row = ch >> 2, qq = ch & 3;
            *(uint4*)&As[row][qq * 8] = *(const uint4*)(Ab + (m0 + row) * K + k0 + qq * 8);
        }
        #pragma unroll
        for (int it = 0; it < (BN == 128 ? 2 : 1); ++it) {
            int ch = tid + it * 256;
            int row = ch >> 2, qq = ch & 3;
            *(uint4*)&Bs[row][qq * 8] = *(const uint4*)(Btb + (n0 + row) * K + k0 + qq * 8);
        }
        __syncthreads();
        bshort8 a0 = *(const bshort8*)&As[wq * 32 + l15][quad * 8];
        bshort8 a1 = *(const bshort8*)&As[wq * 32 + 16 + l15][quad * 8];
        #pragma unroll
        for (int ns = 0; ns < BN / 16; ++ns) {
            bshort8 bfr = *(const bshort8*)&Bs[ns * 16 + l15][quad * 8];
            c[0][ns] = __builtin_amdgcn_mfma_f32_16x16x32_bf16(a0, bfr, c[0][ns], 0, 0, 0);
            c[1][ns] = __builtin_amdgcn_mfma_f32_16x16x32_bf16(a1, bfr, c[1][ns], 0, 0, 0);
        }
        __syncthreads();
    }

    if (EPI == 1) {
        #pragma unroll
        for (int ms = 0; ms < 2; ++ms)
            #pragma unroll
            for (int ns = 0; ns < BN / 16; ++ns) {
                f32x4 v = c[ms][ns];
                const int n = n0 + ns * 16 + l15;
                const int tok0 = m0 + wq * 32 + ms * 16 + quad * 4;
                float sg[4];
                #pragma unroll
                for (int r = 0; r < 4; ++r)
                    sg[r] = 1.f / (1.f + exp2f(-v[r] * L2E_));
                if (n < 256) {
                    const int hh = n >> 4, d = n & 15;
                    #pragma unroll
                    for (int r = 0; r < 4; ++r) {
                        int tok = tok0 + r, bb = tok >> 11, ss = tok & 2047;
                        qg[(((bb * 16 + hh) * 2048) + ss) * 16 + d] = bf16_rne(2.f * sg[r] - 1.f);
                    }
                } else if (n < 320) {
                    const int j = n - 256, kvv = j >> 4, d = j & 15;
                    #pragma unroll
                    for (int r = 0; r < 4; ++r) {
                        int tok = tok0 + r, bb = tok >> 11, ss = tok & 2047;
                        pko[(((bb * 4 + kvv) * 2048) + ss) * 16 + d] = bf16_rne(sg[r]);
                    }
                } else {
                    const int j = n - 320, kvv = j >> 5, d = j & 31;
                    const int bb = tok0 >> 11, ss = tok0 & 2047;
                    const int tl = ss >> 6, ccol = ss & 63;
                    uint2 w; w.x = bf16x2_rne(sg[0], sg[1]); w.y = bf16x2_rne(sg[2], sg[3]);
                    *(uint2*)(pvT + ((((bb * 4 + kvv) * 32) + tl) * 32 + d) * 64 + ccol) = w;
                }
            }
    } else {
        #pragma unroll
        for (int ms = 0; ms < 2; ++ms)
            #pragma unroll
            for (int ns = 0; ns < BN / 16; ++ns) {
                f32x4 v = c[ms][ns];
                const int col = n0 + ns * 16 + l15;
                const int r0 = m0 + wq * 32 + ms * 16 + quad * 4;
                #pragma unroll
                for (int r = 0; r < 4; ++r)
                    out[(r0 + r) * D_ + col] = v[r];
            }
    }
}

// ---------------- Attention: MFMA flash, no-max online softmax ----------------
// Block: 64 queries x one (b,h); wave wq owns queries [wq*16, wq*16+16).
// Per 64-key tile: S^T = mfma(K-frag, qg-frag) (K dim = 16 bits, zero-padded
// to 32); p = exp2(s*log2e - qsum*log2e), masked on the diagonal tile; p is
// repacked (wave-private LDS) into the B-operand of O^T = mfma(V^T, P^T).
// Load balance: block processes qt pair {pair, 31-pair} -> 33 tiles uniform.
struct AttnLDS {
    unsigned short Kt[64][24];   // keys x 16 bits (stride 24: aligned+bank-ok)
    unsigned short qg[64][24];
    unsigned short Vt[32][72];   // vdim x 64 keys (stride 72: b128 at floor)
    unsigned short P[4][16][72]; // per-wave: 16 queries x 64 keys
    float qsum[64];
};

__global__ __launch_bounds__(256, 2) void attn_kernel(
    const unsigned short* __restrict__ qg_g, const unsigned short* __restrict__ pk_g,
    const unsigned short* __restrict__ pvT_g, const float* __restrict__ e0,
    const float* __restrict__ e1, unsigned short* __restrict__ xo)
{
    __shared__ AttnLDS L;
    const int tid = threadIdx.x, l = tid & 63, wq = tid >> 6;
    const int l15 = l & 15, quad = l >> 4;
    const int bh = blockIdx.x & 31, pair = blockIdx.x >> 5;   // pair in [0,16)
    const int b = bh >> 4, h = bh & 15, kv = h >> 2;
    const unsigned short* pkb = pk_g + ((b * 4 + kv) * 2048) * 16;
    // pvT layout: [b*4+kv][tile 32][vdim 32][key 64] -> stride 65536 per (b,kv)
    const unsigned short* pvb = pvT_g + (b * 4 + kv) * 65536;
    const unsigned short* qgb = qg_g + ((b * 16 + h) * 2048) * 16;

    float e0v[8], dEv[8];
    #pragma unroll
    for (int vs = 0; vs < 2; ++vs)
        #pragma unroll
        for (int r = 0; r < 4; ++r) {
            int idx = h * 32 + vs * 16 + quad * 4 + r;
            float a = e0[idx];
            e0v[vs * 4 + r] = a; dEv[vs * 4 + r] = e1[idx] - a;
        }

    const f32x4 zero4 = {0.f, 0.f, 0.f, 0.f};
    const bshort8 zero8 = {0, 0, 0, 0, 0, 0, 0, 0};

    for (int ph = 0; ph < 2; ++ph) {
        const int qt = ph ? (31 - pair) : pair;
        const int qbase = qt * 64;

        if (tid < 128) {   // stage qg rows (32 B each)
            int row = tid >> 1, half = tid & 1;
            *(uint4*)&L.qg[row][half * 8] = *(const uint4*)(qgb + (qbase + row) * 16 + half * 8);
        }
        __syncthreads();
        if (tid < 64) {
            float s = 0.f;
            #pragma unroll
            for (int j = 0; j < 16; ++j) s += bf16_to_f(L.qg[tid][j]);
            L.qsum[tid] = 8.f + 0.5f * s;   // = sum(pq)
        }
        __syncthreads();

        const float qs2 = L.qsum[wq * 16 + l15] * L2E_;
        bshort8 qfrag = zero8;
        if (quad < 2) qfrag = *(const bshort8*)&L.qg[wq * 16 + l15][quad * 8];
        const int q_lane = qbase + wq * 16 + l15;
        f32x4 acc0 = zero4, acc1 = zero4;
        float lsum = 0.f;

        for (int t = 0; t <= qt; ++t) {
            const int t0 = t * 64;
            if (tid < 128) {   // stage K tile
                int row = tid >> 1, half = tid & 1;
                *(uint4*)&L.Kt[row][half * 8] = *(const uint4*)(pkb + (t0 + row) * 16 + half * 8);
            }
            {   // stage Vt tile (blocked global layout: contiguous 4 KB)
                int vd = tid >> 3, ch = tid & 7;
                *(uint4*)&L.Vt[vd][ch * 8] = *(const uint4*)(pvb + t * 2048 + vd * 64 + ch * 8);
            }
            __syncthreads();

            const bool dg = (t == qt);
            f32x4 sc[4];
            #pragma unroll
            for (int ks = 0; ks < 4; ++ks) {
                bshort8 kf = zero8;
                if (quad < 2) kf = *(const bshort8*)&L.Kt[ks * 16 + l15][quad * 8];
                sc[ks] = __builtin_amdgcn_mfma_f32_16x16x32_bf16(kf, qfrag, zero4, 0, 0, 0);
            }
            #pragma unroll
            for (int ks = 0; ks < 4; ++ks) {
                float pv0[4];
                #pragma unroll
                for (int r = 0; r < 4; ++r) {
                    float pp = exp2f(fmaf(sc[ks][r], L2E_, -qs2));
                    if (dg) {
                        int tg = t0 + ks * 16 + quad * 4 + r;
                        if (tg > q_lane) pp = 0.f;
                    }
                    lsum += pp; pv0[r] = pp;
                }
                uint2 w; w.x = bf16x2_rne(pv0[0], pv0[1]); w.y = bf16x2_rne(pv0[2], pv0[3]);
                *(uint2*)&L.P[wq][l15][ks * 16 + quad * 4] = w;
            }
            #pragma unroll
            for (int ks2 = 0; ks2 < 2; ++ks2) {
                bshort8 pf = *(const bshort8*)&L.P[wq][l15][ks2 * 32 + quad * 8];
                bshort8 v0 = *(const bshort8*)&L.Vt[l15][ks2 * 32 + quad * 8];
                bshort8 v1 = *(const bshort8*)&L.Vt[16 + l15][ks2 * 32 + quad * 8];
                acc0 = __builtin_amdgcn_mfma_f32_16x16x32_bf16(v0, pf, acc0, 0, 0, 0);
                acc1 = __builtin_amdgcn_mfma_f32_16x16x32_bf16(v1, pf, acc1, 0, 0, 0);
            }
            __syncthreads();
        }

        lsum += __shfl_xor(lsum, 16);
        lsum += __shfl_xor(lsum, 32);
        const float inv = 1.f / lsum;
        const int tok = b * 2048 + qbase + wq * 16 + l15;
        float o0[4], o1[4];
        #pragma unroll
        for (int r = 0; r < 4; ++r) {
            o0[r] = e0v[r]     + dEv[r]     * (acc0[r] * inv);
            o1[r] = e0v[4 + r] + dEv[4 + r] * (acc1[r] * inv);
        }
        uint2 w0; w0.x = bf16x2_rne(o0[0], o0[1]); w0.y = bf16x2_rne(o0[2], o0[3]);
        uint2 w1; w1.x = bf16x2_rne(o1[0], o1[1]); w1.y = bf16x2_rne(o1[2], o1[3]);
        *(uint2*)(xo + tok * 512 + h * 32 + quad * 4)      = w0;
        *(uint2*)(xo + tok * 512 + h * 32 + 16 + quad * 4) = w1;
        __syncthreads();   // protect LDS before next phase
    }
}

extern "C" void kernel_launch(void* const* d_in, const int* in_sizes, int n_in,
                              void* d_out, int out_size, void* d_ws, size_t ws_size,
                              hipStream_t stream)
{
    const float* hs = (const float*)d_in[0];
    const float* Wq = (const float*)d_in[1];
    const float* Wk = (const float*)d_in[2];
    const float* Wv = (const float*)d_in[3];
    const float* Wo = (const float*)d_in[4];
    const float* e0 = (const float*)d_in[5];
    const float* e1 = (const float*)d_in[6];
    float* out = (float*)d_out;

    char* ws = (char*)d_ws;
    // hs_b occupies [0, 8 MB); xo aliases [0, 4 MB) after proj has consumed hs_b.
    unsigned short* hs_b   = (unsigned short*)(ws);
    unsigned short* xo     = (unsigned short*)(ws);
    unsigned short* Wcat_t = (unsigned short*)(ws + 8388608);
    unsigned short* Wot    = (unsigned short*)(ws + 8388608 + 917504);
    unsigned short* qg     = (unsigned short*)(ws + 10354688);
    unsigned short* pk     = (unsigned short*)(ws + 12451840);
    unsigned short* pvT    = (unsigned short*)(ws + 12976128);

    cvt_hs_kernel<<<2048, 256, 0, stream>>>(hs, hs_b);
    trans_w_kernel<<<240, 256, 0, stream>>>(Wq, Wk, Wv, Wo, Wcat_t, Wot);
    gemm_kernel<64, 1><<<dim3(32, 7), 256, 0, stream>>>(hs_b, Wcat_t, 1024, nullptr, qg, pk, pvT);
    attn_kernel<<<512, 256, 0, stream>>>(qg, pk, pvT, e0, e1, xo);
    gemm_kernel<128, 0><<<dim3(32, 8), 256, 0, stream>>>(xo, Wot, 512, out, nullptr, nullptr, nullptr);
}

// Round 5
// 178.870 us; speedup vs baseline: 9.2996x; 1.0168x over previous
//
#include <hip/hip_runtime.h>
#include <hip/hip_bf16.h>

#define B_    2
#define S_    2048
#define D_    1024
#define H_    16
#define KV_   4
#define QKB_  16
#define VB_   32
#define NTOK  (B_ * S_)   // 4096
#define L2E_  1.44269504088896f

typedef __attribute__((ext_vector_type(8))) short bshort8;
typedef __attribute__((ext_vector_type(4))) float f32x4;

__device__ __forceinline__ unsigned short bf16_rne(float x) {
    unsigned u = __float_as_uint(x);
    return (unsigned short)((u + 0x7FFFu + ((u >> 16) & 1u)) >> 16);
}
__device__ __forceinline__ unsigned bf16x2_rne(float lo, float hi) {
    return (unsigned)bf16_rne(lo) | ((unsigned)bf16_rne(hi) << 16);
}
// sum of the two bf16 halves of a packed uint
__device__ __forceinline__ float sum2bf(unsigned u) {
    return __uint_as_float(u << 16) + __uint_as_float(u & 0xFFFF0000u);
}

// ---------------- Prep 1: hs fp32 -> bf16 ----------------
__global__ __launch_bounds__(256) void cvt_hs_kernel(
    const float* __restrict__ src, unsigned short* __restrict__ dst)
{
    int i = blockIdx.x * 256 + threadIdx.x;      // 8 elems per thread
    const float4* s = (const float4*)src;
    float4 a = s[2 * i], b = s[2 * i + 1];
    uint4 o;
    o.x = bf16x2_rne(a.x, a.y); o.y = bf16x2_rne(a.z, a.w);
    o.z = bf16x2_rne(b.x, b.y); o.w = bf16x2_rne(b.z, b.w);
    ((uint4*)dst)[i] = o;
}

// ---------------- Prep 2: transpose weights to [n][k] bf16 ----------------
// Wcat_t[448][1024]: rows 0-255 Wq cols, 256-319 Wk, 320-447 Wv. Wot[1024][512].
__global__ __launch_bounds__(256) void trans_w_kernel(
    const float* __restrict__ Wq, const float* __restrict__ Wk,
    const float* __restrict__ Wv, const float* __restrict__ Wo,
    unsigned short* __restrict__ Wcat_t, unsigned short* __restrict__ Wot)
{
    __shared__ float T[64][65];
    const int bid = blockIdx.x, t = threadIdx.x;
    const float* src; unsigned short* dst; int K, N, tk, tn, drow0;
    if (bid < 64)       { src = Wq; dst = Wcat_t; K = 1024; N = 256;  int r = bid;       tk = r & 15; tn = r >> 4; drow0 = 0; }
    else if (bid < 80)  { src = Wk; dst = Wcat_t; K = 1024; N = 64;   int r = bid - 64;  tk = r;      tn = 0;      drow0 = 256; }
    else if (bid < 112) { src = Wv; dst = Wcat_t; K = 1024; N = 128;  int r = bid - 80;  tk = r & 15; tn = r >> 4; drow0 = 320; }
    else                { src = Wo; dst = Wot;    K = 512;  N = 1024; int r = bid - 112; tk = r & 7;  tn = r >> 3; drow0 = 0; }
    const int k0 = tk * 64, n0 = tn * 64;
    const int rr = t >> 4, cc = (t & 15) * 4;
    #pragma unroll
    for (int i = 0; i < 4; ++i) {
        float4 v = *(const float4*)(src + (k0 + rr + i * 16) * N + n0 + cc);
        T[rr + i * 16][cc + 0] = v.x; T[rr + i * 16][cc + 1] = v.y;
        T[rr + i * 16][cc + 2] = v.z; T[rr + i * 16][cc + 3] = v.w;
    }
    __syncthreads();
    const int nloc = t >> 2, kc = (t & 3) * 16;
    unsigned o[8];
    #pragma unroll
    for (int j = 0; j < 8; ++j)
        o[j] = bf16x2_rne(T[kc + 2 * j][nloc], T[kc + 2 * j + 1][nloc]);
    unsigned short* dp = dst + (drow0 + n0 + nloc) * K + k0 + kc;
    uint4 w0; w0.x = o[0]; w0.y = o[1]; w0.z = o[2]; w0.w = o[3];
    uint4 w1; w1.x = o[4]; w1.y = o[5]; w1.z = o[6]; w1.w = o[7];
    *(uint4*)(dp) = w0;
    *(uint4*)(dp + 8) = w1;
}

// ---------------- bf16 MFMA GEMM: C[64 x 64] tiles, BK=32 ----------------
// A[M][K] bf16 row-major; Bt[N][K] bf16 (pre-transposed). 4 waves, wave does
// 16 rows x 64 cols. EPI=1: proj epilogue (sigmoid + scatter, qg pre-scaled
// by log2e). EPI=0: f32 out.
template<int EPI>
__global__ __launch_bounds__(256, 4) void gemm_kernel(
    const unsigned short* __restrict__ Ab, const unsigned short* __restrict__ Btb,
    const int K, float* __restrict__ out,
    unsigned short* __restrict__ qg, unsigned short* __restrict__ pko,
    unsigned short* __restrict__ pvT)
{
    __shared__ unsigned short As[64][40];
    __shared__ unsigned short Bs[64][40];
    const int tid = threadIdx.x, l = tid & 63, wq = tid >> 6;
    const int l15 = l & 15, quad = l >> 4;
    const int m0 = blockIdx.x * 64, n0 = blockIdx.y * 64;
    const int srow = tid >> 2, sq = (tid & 3) * 8;
    f32x4 c[4];
    #pragma unroll
    for (int j = 0; j < 4; ++j) c[j] = (f32x4){0.f, 0.f, 0.f, 0.f};

    for (int k0 = 0; k0 < K; k0 += 32) {
        *(uint4*)&As[srow][sq] = *(const uint4*)(Ab  + (m0 + srow) * K + k0 + sq);
        *(uint4*)&Bs[srow][sq] = *(const uint4*)(Btb + (n0 + srow) * K + k0 + sq);
        __syncthreads();
        bshort8 a0 = *(const bshort8*)&As[wq * 16 + l15][quad * 8];
        #pragma unroll
        for (int ns = 0; ns < 4; ++ns) {
            bshort8 bfr = *(const bshort8*)&Bs[ns * 16 + l15][quad * 8];
            c[ns] = __builtin_amdgcn_mfma_f32_16x16x32_bf16(a0, bfr, c[ns], 0, 0, 0);
        }
        __syncthreads();
    }

    const int tok0 = m0 + wq * 16 + quad * 4;
    if (EPI == 1) {
        #pragma unroll
        for (int ns = 0; ns < 4; ++ns) {
            f32x4 v = c[ns];
            const int n = n0 + ns * 16 + l15;
            float sg[4];
            #pragma unroll
            for (int r = 0; r < 4; ++r)
                sg[r] = 1.f / (1.f + exp2f(-v[r] * L2E_));
            if (n < 256) {
                const int hh = n >> 4, d = n & 15;
                #pragma unroll
                for (int r = 0; r < 4; ++r) {
                    int tok = tok0 + r, bb = tok >> 11, ss = tok & 2047;
                    qg[(((bb * 16 + hh) * 2048) + ss) * 16 + d] =
                        bf16_rne(L2E_ * (2.f * sg[r] - 1.f));
                }
            } else if (n < 320) {
                const int j = n - 256, kvv = j >> 4, d = j & 15;
                #pragma unroll
                for (int r = 0; r < 4; ++r) {
                    int tok = tok0 + r, bb = tok >> 11, ss = tok & 2047;
                    pko[(((bb * 4 + kvv) * 2048) + ss) * 16 + d] = bf16_rne(sg[r]);
                }
            } else {
                const int j = n - 320, kvv = j >> 5, d = j & 31;
                const int bb = tok0 >> 11, ss = tok0 & 2047;
                const int tl = ss >> 6, ccol = ss & 63;
                uint2 w; w.x = bf16x2_rne(sg[0], sg[1]); w.y = bf16x2_rne(sg[2], sg[3]);
                *(uint2*)(pvT + ((((bb * 4 + kvv) * 32) + tl) * 32 + d) * 64 + ccol) = w;
            }
        }
    } else {
        #pragma unroll
        for (int ns = 0; ns < 4; ++ns) {
            f32x4 v = c[ns];
            const int col = n0 + ns * 16 + l15;
            #pragma unroll
            for (int r = 0; r < 4; ++r)
                out[(tok0 + r) * D_ + col] = v[r];
        }
    }
}

// ---------------- Attention: MFMA flash ----------------
// Grid 1024 = qt(32) x bh(32). Block = 64 queries; wave wq owns queries
// wq*16..+15 and iterates all key tiles. K double-buffered in LDS (1 barrier
// per tile); V fragments loaded directly from global (L2-resident, no LDS).
// Softmax shift & log2e folded into MFMA k-slot 16: qg holds log2e*(2pq-1)
// (k<16) and -log2e*sum(pq) at k=16; K rows hold 1.0 at k=16. Then
// p = exp2(score) with no per-score fma; per-query-constant bf16 rounding of
// the slot cancels in softmax.
struct AttnLDS {
    unsigned short Kt[2][64][24];  // 6 KB: 16 bits + [16]=1.0 + zero pad
    unsigned short qg[64][24];     // 3 KB: 16 vals + [16]=-l2e*qsum + pad
    unsigned short P[4][16][88];   // 11 KB: stride 88 -> 2-way max (free)
};

__global__ __launch_bounds__(256, 4) void attn_kernel(
    const unsigned short* __restrict__ qg_g, const unsigned short* __restrict__ pk_g,
    const unsigned short* __restrict__ pvT_g, const float* __restrict__ e0,
    const float* __restrict__ e1, unsigned short* __restrict__ xo)
{
    __shared__ AttnLDS L;
    const int tid = threadIdx.x, l = tid & 63, wq = tid >> 6;
    const int l15 = l & 15, quad = l >> 4;
    const int qt = blockIdx.x & 31, bh = blockIdx.x >> 5;
    const int b = bh >> 4, h = bh & 15, kv = h >> 2;
    const int qbase = qt * 64;
    const unsigned short* pkb = pk_g + ((b * 4 + kv) * 2048) * 16;
    const unsigned short* pvb = pvT_g + (b * 4 + kv) * 65536;  // [tile][vd32][key64]
    const unsigned short* qgb = qg_g + ((b * 16 + h) * 2048) * 16;

    const f32x4 zero4 = {0.f, 0.f, 0.f, 0.f};
    const bshort8 zero8 = {0, 0, 0, 0, 0, 0, 0, 0};

    // ---- initial staging: qg rows, K tile 0, const k-slot, qsum slots ----
    if (tid < 128) {
        int row = tid >> 1, half = tid & 1;
        *(uint4*)&L.qg[row][half * 8] = *(const uint4*)(qgb + (qbase + row) * 16 + half * 8);
        uint4 cst; cst.x = 0x3F80u; cst.y = 0u; cst.z = 0u; cst.w = 0u;   // bf16 1.0
        *(uint4*)&L.Kt[tid >> 6][tid & 63][16] = cst;
    } else {
        int t2 = tid - 128, row = t2 >> 1, half = t2 & 1;
        *(uint4*)&L.Kt[0][row][half * 8] = *(const uint4*)(pkb + row * 16 + half * 8);
    }
    if (tid < 64) {
        const uint4* qp = (const uint4*)(qgb + (qbase + tid) * 16);
        uint4 u0 = qp[0], u1 = qp[1];
        float s = sum2bf(u0.x) + sum2bf(u0.y) + sum2bf(u0.z) + sum2bf(u0.w)
                + sum2bf(u1.x) + sum2bf(u1.y) + sum2bf(u1.z) + sum2bf(u1.w);
        // slot = -l2e*qsum = -8*l2e - 0.5*sum(qg')
        uint4 sv; sv.x = (unsigned)bf16_rne(-8.f * L2E_ - 0.5f * s);
        sv.y = 0u; sv.z = 0u; sv.w = 0u;
        *(uint4*)&L.qg[tid][16] = sv;
    }
    __syncthreads();

    bshort8 qfrag = zero8;
    if (quad < 3) qfrag = *(const bshort8*)&L.qg[wq * 16 + l15][quad * 8];

    f32x4 acc0 = zero4, acc1 = zero4;
    float lsum = 0.f;

    for (int t = 0; t < qt; ++t) {
        if (tid < 128) {   // stage K(t+1) into the other buffer
            int row = tid >> 1, half = tid & 1;
            *(uint4*)&L.Kt[(t + 1) & 1][row][half * 8] =
                *(const uint4*)(pkb + ((t + 1) * 64 + row) * 16 + half * 8);
        }
        const unsigned short* Kb = &L.Kt[t & 1][0][0];
        const unsigned short* vb = pvb + t * 2048 + l15 * 64 + quad * 8;
        bshort8 vlo0 = *(const bshort8*)(vb);
        bshort8 vlo1 = *(const bshort8*)(vb + 32);
        bshort8 vhi0 = *(const bshort8*)(vb + 1024);
        bshort8 vhi1 = *(const bshort8*)(vb + 1056);

        f32x4 sc[4];
        #pragma unroll
        for (int ks = 0; ks < 4; ++ks) {
            bshort8 kf = zero8;
            if (quad < 3) kf = *(const bshort8*)(Kb + (ks * 16 + l15) * 24 + quad * 8);
            sc[ks] = __builtin_amdgcn_mfma_f32_16x16x32_bf16(kf, qfrag, zero4, 0, 0, 0);
        }
        #pragma unroll
        for (int ks = 0; ks < 4; ++ks) {
            float p0 = exp2f(sc[ks][0]), p1 = exp2f(sc[ks][1]);
            float p2 = exp2f(sc[ks][2]), p3 = exp2f(sc[ks][3]);
            lsum += p0 + p1 + p2 + p3;
            uint2 w; w.x = bf16x2_rne(p0, p1); w.y = bf16x2_rne(p2, p3);
            *(uint2*)&L.P[wq][l15][ks * 16 + quad * 4] = w;
        }
        {
            bshort8 pf0 = *(const bshort8*)&L.P[wq][l15][quad * 8];
            bshort8 pf1 = *(const bshort8*)&L.P[wq][l15][32 + quad * 8];
            acc0 = __builtin_amdgcn_mfma_f32_16x16x32_bf16(vlo0, pf0, acc0, 0, 0, 0);
            acc1 = __builtin_amdgcn_mfma_f32_16x16x32_bf16(vhi0, pf0, acc1, 0, 0, 0);
            acc0 = __builtin_amdgcn_mfma_f32_16x16x32_bf16(vlo1, pf1, acc0, 0, 0, 0);
            acc1 = __builtin_amdgcn_mfma_f32_16x16x32_bf16(vhi1, pf1, acc1, 0, 0, 0);
        }
        __syncthreads();
    }

    // ---- peeled diagonal tile t = qt (causal mask) ----
    {
        const unsigned short* Kb = &L.Kt[qt & 1][0][0];
        const unsigned short* vb = pvb + qt * 2048 + l15 * 64 + quad * 8;
        bshort8 vlo0 = *(const bshort8*)(vb);
        bshort8 vlo1 = *(const bshort8*)(vb + 32);
        bshort8 vhi0 = *(const bshort8*)(vb + 1024);
        bshort8 vhi1 = *(const bshort8*)(vb + 1056);
        const int q_lane = qbase + wq * 16 + l15;

        f32x4 sc[4];
        #pragma unroll
        for (int ks = 0; ks < 4; ++ks) {
            bshort8 kf = zero8;
            if (quad < 3) kf = *(const bshort8*)(Kb + (ks * 16 + l15) * 24 + quad * 8);
            sc[ks] = __builtin_amdgcn_mfma_f32_16x16x32_bf16(kf, qfrag, zero4, 0, 0, 0);
        }
        #pragma unroll
        for (int ks = 0; ks < 4; ++ks) {
            float pv0[4];
            #pragma unroll
            for (int r = 0; r < 4; ++r) {
                const int tg = qbase + ks * 16 + quad * 4 + r;
                float pp = (tg <= q_lane) ? exp2f(sc[ks][r]) : 0.f;
                lsum += pp; pv0[r] = pp;
            }
            uint2 w; w.x = bf16x2_rne(pv0[0], pv0[1]); w.y = bf16x2_rne(pv0[2], pv0[3]);
            *(uint2*)&L.P[wq][l15][ks * 16 + quad * 4] = w;
        }
        {
            bshort8 pf0 = *(const bshort8*)&L.P[wq][l15][quad * 8];
            bshort8 pf1 = *(const bshort8*)&L.P[wq][l15][32 + quad * 8];
            acc0 = __builtin_amdgcn_mfma_f32_16x16x32_bf16(vlo0, pf0, acc0, 0, 0, 0);
            acc1 = __builtin_amdgcn_mfma_f32_16x16x32_bf16(vhi0, pf0, acc1, 0, 0, 0);
            acc0 = __builtin_amdgcn_mfma_f32_16x16x32_bf16(vlo1, pf1, acc0, 0, 0, 0);
            acc1 = __builtin_amdgcn_mfma_f32_16x16x32_bf16(vhi1, pf1, acc1, 0, 0, 0);
        }
    }

    lsum += __shfl_xor(lsum, 16);
    lsum += __shfl_xor(lsum, 32);
    const float inv = 1.f / lsum;

    float e0v[8], dEv[8];
    #pragma unroll
    for (int vs = 0; vs < 2; ++vs)
        #pragma unroll
        for (int r = 0; r < 4; ++r) {
            int idx = h * 32 + vs * 16 + quad * 4 + r;
            float a = e0[idx];
            e0v[vs * 4 + r] = a; dEv[vs * 4 + r] = e1[idx] - a;
        }
    const int tok = b * 2048 + qbase + wq * 16 + l15;
    float o0[4], o1[4];
    #pragma unroll
    for (int r = 0; r < 4; ++r) {
        o0[r] = e0v[r]     + dEv[r]     * (acc0[r] * inv);
        o1[r] = e0v[4 + r] + dEv[4 + r] * (acc1[r] * inv);
    }
    uint2 w0; w0.x = bf16x2_rne(o0[0], o0[1]); w0.y = bf16x2_rne(o0[2], o0[3]);
    uint2 w1; w1.x = bf16x2_rne(o1[0], o1[1]); w1.y = bf16x2_rne(o1[2], o1[3]);
    *(uint2*)(xo + tok * 512 + h * 32 + quad * 4)      = w0;
    *(uint2*)(xo + tok * 512 + h * 32 + 16 + quad * 4) = w1;
}

extern "C" void kernel_launch(void* const* d_in, const int* in_sizes, int n_in,
                              void* d_out, int out_size, void* d_ws, size_t ws_size,
                              hipStream_t stream)
{
    const float* hs = (const float*)d_in[0];
    const float* Wq = (const float*)d_in[1];
    const float* Wk = (const float*)d_in[2];
    const float* Wv = (const float*)d_in[3];
    const float* Wo = (const float*)d_in[4];
    const float* e0 = (const float*)d_in[5];
    const float* e1 = (const float*)d_in[6];
    float* out = (float*)d_out;

    char* ws = (char*)d_ws;
    // hs_b occupies [0, 8 MB); xo aliases [0, 4 MB) after proj has consumed hs_b.
    unsigned short* hs_b   = (unsigned short*)(ws);
    unsigned short* xo     = (unsigned short*)(ws);
    unsigned short* Wcat_t = (unsigned short*)(ws + 8388608);
    unsigned short* Wot    = (unsigned short*)(ws + 8388608 + 917504);
    unsigned short* qg     = (unsigned short*)(ws + 10354688);
    unsigned short* pk     = (unsigned short*)(ws + 12451840);
    unsigned short* pvT    = (unsigned short*)(ws + 12976128);

    cvt_hs_kernel<<<2048, 256, 0, stream>>>(hs, hs_b);
    trans_w_kernel<<<240, 256, 0, stream>>>(Wq, Wk, Wv, Wo, Wcat_t, Wot);
    gemm_kernel<1><<<dim3(64, 7), 256, 0, stream>>>(hs_b, Wcat_t, 1024, nullptr, qg, pk, pvT);
    attn_kernel<<<1024, 256, 0, stream>>>(qg, pk, pvT, e0, e1, xo);
    gemm_kernel<0><<<dim3(64, 16), 256, 0, stream>>>(xo, Wot, 512, out, nullptr, nullptr, nullptr);
}

// Round 6
// 147.040 us; speedup vs baseline: 11.3128x; 1.2165x over previous
//
#include <hip/hip_runtime.h>
#include <hip/hip_bf16.h>

#define B_    2
#define S_    2048
#define D_    1024
#define H_    16
#define KV_   4
#define QKB_  16
#define VB_   32
#define NTOK  (B_ * S_)   // 4096
#define L2E_  1.44269504088896f

typedef __attribute__((ext_vector_type(8))) short bshort8;
typedef __attribute__((ext_vector_type(4))) float f32x4;

__device__ __forceinline__ unsigned short bf16_rne(float x) {
    unsigned u = __float_as_uint(x);
    return (unsigned short)((u + 0x7FFFu + ((u >> 16) & 1u)) >> 16);
}
__device__ __forceinline__ unsigned bf16x2_rne(float lo, float hi) {
    return (unsigned)bf16_rne(lo) | ((unsigned)bf16_rne(hi) << 16);
}
__device__ __forceinline__ float sum2bf(unsigned u) {
    return __uint_as_float(u << 16) + __uint_as_float(u & 0xFFFF0000u);
}
// async global->LDS, 16 B per lane; LDS dest = wave-uniform base + lane*16
__device__ __forceinline__ void stage16(const unsigned short* g, unsigned short* l) {
    __builtin_amdgcn_global_load_lds(
        (const __attribute__((address_space(1))) void*)g,
        (__attribute__((address_space(3))) void*)l, 16, 0, 0);
}

// ---------------- Prep 1: hs fp32 -> bf16 ----------------
__global__ __launch_bounds__(256) void cvt_hs_kernel(
    const float* __restrict__ src, unsigned short* __restrict__ dst)
{
    int i = blockIdx.x * 256 + threadIdx.x;
    const float4* s = (const float4*)src;
    float4 a = s[2 * i], b = s[2 * i + 1];
    uint4 o;
    o.x = bf16x2_rne(a.x, a.y); o.y = bf16x2_rne(a.z, a.w);
    o.z = bf16x2_rne(b.x, b.y); o.w = bf16x2_rne(b.z, b.w);
    ((uint4*)dst)[i] = o;
}

// ---------------- Prep 2: transpose weights to [n][k] bf16 ----------------
__global__ __launch_bounds__(256) void trans_w_kernel(
    const float* __restrict__ Wq, const float* __restrict__ Wk,
    const float* __restrict__ Wv, const float* __restrict__ Wo,
    unsigned short* __restrict__ Wcat_t, unsigned short* __restrict__ Wot)
{
    __shared__ float T[64][65];
    const int bid = blockIdx.x, t = threadIdx.x;
    const float* src; unsigned short* dst; int K, N, tk, tn, drow0;
    if (bid < 64)       { src = Wq; dst = Wcat_t; K = 1024; N = 256;  int r = bid;       tk = r & 15; tn = r >> 4; drow0 = 0; }
    else if (bid < 80)  { src = Wk; dst = Wcat_t; K = 1024; N = 64;   int r = bid - 64;  tk = r;      tn = 0;      drow0 = 256; }
    else if (bid < 112) { src = Wv; dst = Wcat_t; K = 1024; N = 128;  int r = bid - 80;  tk = r & 15; tn = r >> 4; drow0 = 320; }
    else                { src = Wo; dst = Wot;    K = 512;  N = 1024; int r = bid - 112; tk = r & 7;  tn = r >> 3; drow0 = 0; }
    const int k0 = tk * 64, n0 = tn * 64;
    const int rr = t >> 4, cc = (t & 15) * 4;
    #pragma unroll
    for (int i = 0; i < 4; ++i) {
        float4 v = *(const float4*)(src + (k0 + rr + i * 16) * N + n0 + cc);
        T[rr + i * 16][cc + 0] = v.x; T[rr + i * 16][cc + 1] = v.y;
        T[rr + i * 16][cc + 2] = v.z; T[rr + i * 16][cc + 3] = v.w;
    }
    __syncthreads();
    const int nloc = t >> 2, kc = (t & 3) * 16;
    unsigned o[8];
    #pragma unroll
    for (int j = 0; j < 8; ++j)
        o[j] = bf16x2_rne(T[kc + 2 * j][nloc], T[kc + 2 * j + 1][nloc]);
    unsigned short* dp = dst + (drow0 + n0 + nloc) * K + k0 + kc;
    uint4 w0; w0.x = o[0]; w0.y = o[1]; w0.z = o[2]; w0.w = o[3];
    uint4 w1; w1.x = o[4]; w1.y = o[5]; w1.z = o[6]; w1.w = o[7];
    *(uint4*)(dp) = w0;
    *(uint4*)(dp + 8) = w1;
}

// ---------------- proj GEMM: 64x128 tile, BK=64, gl_lds + XOR-8 swizzle --------
// A = hs_b[4096][1024], Bt = Wcat_t[448(->512 pad)][1024]. Epilogue: sigmoid +
// scatter to qg (log2e*(2s-1)), pk, pvT.  LDS chunk c of row r holds global
// chunk c^(r&7) (swizzle applied on the global address; gl_lds dest is linear).
__global__ __launch_bounds__(256, 2) void proj_gemm(
    const unsigned short* __restrict__ Ab, const unsigned short* __restrict__ Btb,
    unsigned short* __restrict__ qg, unsigned short* __restrict__ pko,
    unsigned short* __restrict__ pvT)
{
    __shared__ unsigned short As[64 * 64];    //  8 KB
    __shared__ unsigned short Bs[128 * 64];   // 16 KB
    const int tid = threadIdx.x, l = tid & 63, w = tid >> 6;
    const int l15 = l & 15, quad = l >> 4;
    const int m0 = blockIdx.x * 64, n0 = blockIdx.y * 128;
    const int wr = w & 1, wc = w >> 1;
    const int sr8 = l >> 3, sc8 = l & 7;      // staging: 8 rows x 8 chunks per issue
    f32x4 c[2][4];
    #pragma unroll
    for (int i = 0; i < 2; ++i)
        #pragma unroll
        for (int j = 0; j < 4; ++j) c[i][j] = (f32x4){0.f, 0.f, 0.f, 0.f};

    for (int k0 = 0; k0 < 1024; k0 += 64) {
        {   // A: 8 issues of 8 rows; wave w does issues w and 4+w
            int R0 = w * 8, r0 = R0 + sr8;
            stage16(Ab + (m0 + r0) * 1024 + k0 + (sc8 ^ (r0 & 7)) * 8, &As[R0 * 64]);
            int R1 = 32 + w * 8, r1 = R1 + sr8;
            stage16(Ab + (m0 + r1) * 1024 + k0 + (sc8 ^ (r1 & 7)) * 8, &As[R1 * 64]);
        }
        #pragma unroll
        for (int j = 0; j < 4; ++j) {   // B: 16 issues; wave w does w+4j
            int R = j * 32 + w * 8, r = R + sr8;
            stage16(Btb + (n0 + r) * 1024 + k0 + (sc8 ^ (r & 7)) * 8, &Bs[R * 64]);
        }
        __syncthreads();
        #pragma unroll
        for (int kh = 0; kh < 2; ++kh) {
            bshort8 a[2], b[4];
            #pragma unroll
            for (int ar = 0; ar < 2; ++ar) {
                int row = wr * 32 + ar * 16 + l15;
                a[ar] = *(const bshort8*)&As[row * 64 + (((kh * 4 + quad) ^ (row & 7)) * 8)];
            }
            #pragma unroll
            for (int bc = 0; bc < 4; ++bc) {
                int row = wc * 64 + bc * 16 + l15;
                b[bc] = *(const bshort8*)&Bs[row * 64 + (((kh * 4 + quad) ^ (row & 7)) * 8)];
            }
            #pragma unroll
            for (int ar = 0; ar < 2; ++ar)
                #pragma unroll
                for (int bc = 0; bc < 4; ++bc)
                    c[ar][bc] = __builtin_amdgcn_mfma_f32_16x16x32_bf16(a[ar], b[bc], c[ar][bc], 0, 0, 0);
        }
        __syncthreads();
    }

    #pragma unroll
    for (int ar = 0; ar < 2; ++ar)
        #pragma unroll
        for (int bc = 0; bc < 4; ++bc) {
            f32x4 v = c[ar][bc];
            const int n = n0 + wc * 64 + bc * 16 + l15;
            if (n >= 448) continue;
            const int tok0 = m0 + wr * 32 + ar * 16 + quad * 4;
            float sg[4];
            #pragma unroll
            for (int r = 0; r < 4; ++r)
                sg[r] = 1.f / (1.f + exp2f(-v[r] * L2E_));
            if (n < 256) {
                const int hh = n >> 4, d = n & 15;
                #pragma unroll
                for (int r = 0; r < 4; ++r) {
                    int tok = tok0 + r, bb = tok >> 11, ss = tok & 2047;
                    qg[(((bb * 16 + hh) * 2048) + ss) * 16 + d] =
                        bf16_rne(L2E_ * (2.f * sg[r] - 1.f));
                }
            } else if (n < 320) {
                const int j = n - 256, kvv = j >> 4, d = j & 15;
                #pragma unroll
                for (int r = 0; r < 4; ++r) {
                    int tok = tok0 + r, bb = tok >> 11, ss = tok & 2047;
                    pko[(((bb * 4 + kvv) * 2048) + ss) * 16 + d] = bf16_rne(sg[r]);
                }
            } else {
                const int j = n - 320, kvv = j >> 5, d = j & 31;
                const int bb = tok0 >> 11, ss = tok0 & 2047;
                const int tl = ss >> 6, ccol = ss & 63;
                uint2 wv; wv.x = bf16x2_rne(sg[0], sg[1]); wv.y = bf16x2_rne(sg[2], sg[3]);
                *(uint2*)(pvT + ((((bb * 4 + kvv) * 32) + tl) * 32 + d) * 64 + ccol) = wv;
            }
        }
}

// ---------------- outproj GEMM: 128x128 tile, BK=64, gl_lds + XOR-8 swizzle ----
// A = xo[4096][512] bf16, Bt = Wot[1024][512] bf16, out fp32 [4096][1024].
__global__ __launch_bounds__(256, 2) void outproj_gemm(
    const unsigned short* __restrict__ Ab, const unsigned short* __restrict__ Btb,
    float* __restrict__ out)
{
    __shared__ unsigned short As[128 * 64];   // 16 KB
    __shared__ unsigned short Bs[128 * 64];   // 16 KB
    const int tid = threadIdx.x, l = tid & 63, w = tid >> 6;
    const int l15 = l & 15, quad = l >> 4;
    const int m0 = blockIdx.x * 128, n0 = blockIdx.y * 128;
    const int wr = w & 1, wc = w >> 1;
    const int sr8 = l >> 3, sc8 = l & 7;
    f32x4 c[4][4];
    #pragma unroll
    for (int i = 0; i < 4; ++i)
        #pragma unroll
        for (int j = 0; j < 4; ++j) c[i][j] = (f32x4){0.f, 0.f, 0.f, 0.f};

    for (int k0 = 0; k0 < 512; k0 += 64) {
        #pragma unroll
        for (int j = 0; j < 4; ++j) {
            int R = j * 32 + w * 8, r = R + sr8;
            stage16(Ab  + (m0 + r) * 512 + k0 + (sc8 ^ (r & 7)) * 8, &As[R * 64]);
            stage16(Btb + (n0 + r) * 512 + k0 + (sc8 ^ (r & 7)) * 8, &Bs[R * 64]);
        }
        __syncthreads();
        #pragma unroll
        for (int kh = 0; kh < 2; ++kh) {
            bshort8 a[4], b[4];
            #pragma unroll
            for (int ar = 0; ar < 4; ++ar) {
                int row = wr * 64 + ar * 16 + l15;
                a[ar] = *(const bshort8*)&As[row * 64 + (((kh * 4 + quad) ^ (row & 7)) * 8)];
            }
            #pragma unroll
            for (int bc = 0; bc < 4; ++bc) {
                int row = wc * 64 + bc * 16 + l15;
                b[bc] = *(const bshort8*)&Bs[row * 64 + (((kh * 4 + quad) ^ (row & 7)) * 8)];
            }
            #pragma unroll
            for (int ar = 0; ar < 4; ++ar)
                #pragma unroll
                for (int bc = 0; bc < 4; ++bc)
                    c[ar][bc] = __builtin_amdgcn_mfma_f32_16x16x32_bf16(a[ar], b[bc], c[ar][bc], 0, 0, 0);
        }
        __syncthreads();
    }

    #pragma unroll
    for (int ar = 0; ar < 4; ++ar)
        #pragma unroll
        for (int bc = 0; bc < 4; ++bc) {
            f32x4 v = c[ar][bc];
            const int col = n0 + wc * 64 + bc * 16 + l15;
            const int r0 = m0 + wr * 64 + ar * 16 + quad * 4;
            #pragma unroll
            for (int r = 0; r < 4; ++r)
                out[(r0 + r) * D_ + col] = v[r];
        }
}

// ---------------- Attention: MFMA flash (balanced qt swizzle) ----------------
struct AttnLDS {
    unsigned short Kt[2][64][24];
    unsigned short qg[64][24];
    unsigned short P[4][16][88];
};

__global__ __launch_bounds__(256, 4) void attn_kernel(
    const unsigned short* __restrict__ qg_g, const unsigned short* __restrict__ pk_g,
    const unsigned short* __restrict__ pvT_g, const float* __restrict__ e0,
    const float* __restrict__ e1, unsigned short* __restrict__ xo)
{
    __shared__ AttnLDS L;
    const int tid = threadIdx.x, l = tid & 63, wq = tid >> 6;
    const int l15 = l & 15, quad = l >> 4;
    // balanced mapping: CU's 4 resident blocks (g, g+256, g+512, g+768) get
    // qt {r, 31-r, 8+r, 23-r} -> total work 66 tile-iters per CU, uniform.
    const int g = blockIdx.x;
    const int idx = g & 255, kg = g >> 8;
    const int bh = idx & 31, rr = idx >> 5;
    int qt;
    if      (kg == 0) qt = rr;
    else if (kg == 1) qt = 31 - rr;
    else if (kg == 2) qt = 8 + rr;
    else              qt = 23 - rr;
    const int b = bh >> 4, h = bh & 15, kv = h >> 2;
    const int qbase = qt * 64;
    const unsigned short* pkb = pk_g + ((b * 4 + kv) * 2048) * 16;
    const unsigned short* pvb = pvT_g + (b * 4 + kv) * 65536;  // [tile][vd32][key64]
    const unsigned short* qgb = qg_g + ((b * 16 + h) * 2048) * 16;

    const f32x4 zero4 = {0.f, 0.f, 0.f, 0.f};
    const bshort8 zero8 = {0, 0, 0, 0, 0, 0, 0, 0};

    if (tid < 128) {
        int row = tid >> 1, half = tid & 1;
        *(uint4*)&L.qg[row][half * 8] = *(const uint4*)(qgb + (qbase + row) * 16 + half * 8);
        uint4 cst; cst.x = 0x3F80u; cst.y = 0u; cst.z = 0u; cst.w = 0u;   // bf16 1.0
        *(uint4*)&L.Kt[tid >> 6][tid & 63][16] = cst;
    } else {
        int t2 = tid - 128, row = t2 >> 1, half = t2 & 1;
        *(uint4*)&L.Kt[0][row][half * 8] = *(const uint4*)(pkb + row * 16 + half * 8);
    }
    if (tid < 64) {
        const uint4* qp = (const uint4*)(qgb + (qbase + tid) * 16);
        uint4 u0 = qp[0], u1 = qp[1];
        float s = sum2bf(u0.x) + sum2bf(u0.y) + sum2bf(u0.z) + sum2bf(u0.w)
                + sum2bf(u1.x) + sum2bf(u1.y) + sum2bf(u1.z) + sum2bf(u1.w);
        uint4 sv; sv.x = (unsigned)bf16_rne(-8.f * L2E_ - 0.5f * s);
        sv.y = 0u; sv.z = 0u; sv.w = 0u;
        *(uint4*)&L.qg[tid][16] = sv;
    }
    __syncthreads();

    bshort8 qfrag = zero8;
    if (quad < 3) qfrag = *(const bshort8*)&L.qg[wq * 16 + l15][quad * 8];

    f32x4 acc0 = zero4, acc1 = zero4;
    float lsum = 0.f;

    for (int t = 0; t < qt; ++t) {
        if (tid < 128) {
            int row = tid >> 1, half = tid & 1;
            *(uint4*)&L.Kt[(t + 1) & 1][row][half * 8] =
                *(const uint4*)(pkb + ((t + 1) * 64 + row) * 16 + half * 8);
        }
        const unsigned short* Kb = &L.Kt[t & 1][0][0];
        const unsigned short* vb = pvb + t * 2048 + l15 * 64 + quad * 8;
        bshort8 vlo0 = *(const bshort8*)(vb);
        bshort8 vlo1 = *(const bshort8*)(vb + 32);
        bshort8 vhi0 = *(const bshort8*)(vb + 1024);
        bshort8 vhi1 = *(const bshort8*)(vb + 1056);

        f32x4 sc[4];
        #pragma unroll
        for (int ks = 0; ks < 4; ++ks) {
            bshort8 kf = zero8;
            if (quad < 3) kf = *(const bshort8*)(Kb + (ks * 16 + l15) * 24 + quad * 8);
            sc[ks] = __builtin_amdgcn_mfma_f32_16x16x32_bf16(kf, qfrag, zero4, 0, 0, 0);
        }
        #pragma unroll
        for (int ks = 0; ks < 4; ++ks) {
            float p0 = exp2f(sc[ks][0]), p1 = exp2f(sc[ks][1]);
            float p2 = exp2f(sc[ks][2]), p3 = exp2f(sc[ks][3]);
            lsum += p0 + p1 + p2 + p3;
            uint2 wv; wv.x = bf16x2_rne(p0, p1); wv.y = bf16x2_rne(p2, p3);
            *(uint2*)&L.P[wq][l15][ks * 16 + quad * 4] = wv;
        }
        {
            bshort8 pf0 = *(const bshort8*)&L.P[wq][l15][quad * 8];
            bshort8 pf1 = *(const bshort8*)&L.P[wq][l15][32 + quad * 8];
            acc0 = __builtin_amdgcn_mfma_f32_16x16x32_bf16(vlo0, pf0, acc0, 0, 0, 0);
            acc1 = __builtin_amdgcn_mfma_f32_16x16x32_bf16(vhi0, pf0, acc1, 0, 0, 0);
            acc0 = __builtin_amdgcn_mfma_f32_16x16x32_bf16(vlo1, pf1, acc0, 0, 0, 0);
            acc1 = __builtin_amdgcn_mfma_f32_16x16x32_bf16(vhi1, pf1, acc1, 0, 0, 0);
        }
        __syncthreads();
    }

    {   // peeled diagonal tile t = qt
        const unsigned short* Kb = &L.Kt[qt & 1][0][0];
        const unsigned short* vb = pvb + qt * 2048 + l15 * 64 + quad * 8;
        bshort8 vlo0 = *(const bshort8*)(vb);
        bshort8 vlo1 = *(const bshort8*)(vb + 32);
        bshort8 vhi0 = *(const bshort8*)(vb + 1024);
        bshort8 vhi1 = *(const bshort8*)(vb + 1056);
        const int q_lane = qbase + wq * 16 + l15;

        f32x4 sc[4];
        #pragma unroll
        for (int ks = 0; ks < 4; ++ks) {
            bshort8 kf = zero8;
            if (quad < 3) kf = *(const bshort8*)(Kb + (ks * 16 + l15) * 24 + quad * 8);
            sc[ks] = __builtin_amdgcn_mfma_f32_16x16x32_bf16(kf, qfrag, zero4, 0, 0, 0);
        }
        #pragma unroll
        for (int ks = 0; ks < 4; ++ks) {
            float pv0[4];
            #pragma unroll
            for (int r = 0; r < 4; ++r) {
                const int tg = qbase + ks * 16 + quad * 4 + r;
                float pp = (tg <= q_lane) ? exp2f(sc[ks][r]) : 0.f;
                lsum += pp; pv0[r] = pp;
            }
            uint2 wv; wv.x = bf16x2_rne(pv0[0], pv0[1]); wv.y = bf16x2_rne(pv0[2], pv0[3]);
            *(uint2*)&L.P[wq][l15][ks * 16 + quad * 4] = wv;
        }
        {
            bshort8 pf0 = *(const bshort8*)&L.P[wq][l15][quad * 8];
            bshort8 pf1 = *(const bshort8*)&L.P[wq][l15][32 + quad * 8];
            acc0 = __builtin_amdgcn_mfma_f32_16x16x32_bf16(vlo0, pf0, acc0, 0, 0, 0);
            acc1 = __builtin_amdgcn_mfma_f32_16x16x32_bf16(vhi0, pf0, acc1, 0, 0, 0);
            acc0 = __builtin_amdgcn_mfma_f32_16x16x32_bf16(vlo1, pf1, acc0, 0, 0, 0);
            acc1 = __builtin_amdgcn_mfma_f32_16x16x32_bf16(vhi1, pf1, acc1, 0, 0, 0);
        }
    }

    lsum += __shfl_xor(lsum, 16);
    lsum += __shfl_xor(lsum, 32);
    const float inv = 1.f / lsum;

    float e0v[8], dEv[8];
    #pragma unroll
    for (int vs = 0; vs < 2; ++vs)
        #pragma unroll
        for (int r = 0; r < 4; ++r) {
            int idx2 = h * 32 + vs * 16 + quad * 4 + r;
            float a = e0[idx2];
            e0v[vs * 4 + r] = a; dEv[vs * 4 + r] = e1[idx2] - a;
        }
    const int tok = b * 2048 + qbase + wq * 16 + l15;
    float o0[4], o1[4];
    #pragma unroll
    for (int r = 0; r < 4; ++r) {
        o0[r] = e0v[r]     + dEv[r]     * (acc0[r] * inv);
        o1[r] = e0v[4 + r] + dEv[4 + r] * (acc1[r] * inv);
    }
    uint2 w0; w0.x = bf16x2_rne(o0[0], o0[1]); w0.y = bf16x2_rne(o0[2], o0[3]);
    uint2 w1; w1.x = bf16x2_rne(o1[0], o1[1]); w1.y = bf16x2_rne(o1[2], o1[3]);
    *(uint2*)(xo + tok * 512 + h * 32 + quad * 4)      = w0;
    *(uint2*)(xo + tok * 512 + h * 32 + 16 + quad * 4) = w1;
}

extern "C" void kernel_launch(void* const* d_in, const int* in_sizes, int n_in,
                              void* d_out, int out_size, void* d_ws, size_t ws_size,
                              hipStream_t stream)
{
    const float* hs = (const float*)d_in[0];
    const float* Wq = (const float*)d_in[1];
    const float* Wk = (const float*)d_in[2];
    const float* Wv = (const float*)d_in[3];
    const float* Wo = (const float*)d_in[4];
    const float* e0 = (const float*)d_in[5];
    const float* e1 = (const float*)d_in[6];
    float* out = (float*)d_out;

    char* ws = (char*)d_ws;
    unsigned short* hs_b   = (unsigned short*)(ws);
    unsigned short* xo     = (unsigned short*)(ws);
    unsigned short* Wcat_t = (unsigned short*)(ws + 8388608);
    unsigned short* Wot    = (unsigned short*)(ws + 8388608 + 917504);
    unsigned short* qg     = (unsigned short*)(ws + 10354688);
    unsigned short* pk     = (unsigned short*)(ws + 12451840);
    unsigned short* pvT    = (unsigned short*)(ws + 12976128);

    cvt_hs_kernel<<<2048, 256, 0, stream>>>(hs, hs_b);
    trans_w_kernel<<<240, 256, 0, stream>>>(Wq, Wk, Wv, Wo, Wcat_t, Wot);
    proj_gemm<<<dim3(64, 4), 256, 0, stream>>>(hs_b, Wcat_t, qg, pk, pvT);
    attn_kernel<<<1024, 256, 0, stream>>>(qg, pk, pvT, e0, e1, xo);
    outproj_gemm<<<dim3(32, 8), 256, 0, stream>>>(xo, Wot, out);
}